// Round 7
// baseline (159.947 us; speedup 1.0000x reference)
//
#include <hip/hip_runtime.h>

// Problem: B=4, A=160000 anchors, G=64 gt boxes.
// outputs (concat flat): labels [B,A] f32, matched_gt_boxes [B,A,4] f32
constexpr int NB = 4;
constexpr int NA = 160000;
constexpr int NG = 64;

// Two-dispatch scheme:
//  k_part   : 512-thr blocks (8 waves) — 4 blocks/CU co-resident (1024-thr
//             blocks cap at 1 block/CU = 50% occupancy, observed r4-r6).
//             Anchors+areas LDS-staged; per-block partial per gt; LAST block
//             per batch (module epoch counter, replay-safe) reduces all
//             partials -> haux[b][g] = {garea, highest}.
//  k_assign2: 1 anchor/thread, 2500 blocks; gt data via wave-uniform s_load;
//             LDS only for the cl-indexed epilogue (barrier after main loop).
//
// Preferred P1=500 (2000 blocks, 40 anchors/wave) needs 1 MB ws; fallback
// P1=250 (1000 blocks, 80 anchors/wave) needs 512 KB (proven available).

// Module-scope counter: zero-initialized at module load, counted MODULO P1
// -> "last block per batch" works for every graph replay without a memset.
__device__ int g_ctr[NB];

// --- exact-rounding helpers -------------------------------------------------
// contract(off): stop fma fusion that would change rounding vs numpy.
__device__ __forceinline__ float box_area(float x0, float y0, float x1, float y1) {
#pragma clang fp contract(off)
    return (x1 - x0) * (y1 - y0);
}

// inter/denom with the exact op order of the numpy reference; shared by both
// kernels so phase-1's deferred quotient is bit-identical to phase-2's.
__device__ __forceinline__ void inter_denom(float gx0, float gy0, float gx1, float gy1, float garea,
                                            float ax0, float ay0, float ax1, float ay1, float aarea,
                                            float& inter, float& denom) {
#pragma clang fp contract(off)
    float ltx = fmaxf(gx0, ax0);
    float lty = fmaxf(gy0, ay0);
    float rbx = fminf(gx1, ax1);
    float rby = fminf(gy1, ay1);
    float w = fmaxf(rbx - ltx, 0.0f);
    float h = fmaxf(rby - lty, 0.0f);
    inter = w * h;
    float s = garea + aarea;        // numpy: area_gt + area_anchor
    denom = s - inter;
}

// exact comparison  i1/d1 > i2/d2  (all >= 0, d > 0), pure f32:
// FMA two-product gives the EXACT products p+e; ordering decided on the
// rounded products, ties broken on the exact tails (real-number ordering).
// Harness-validated bit-exact (absmax = 0.0, rounds 1-6).
__device__ __forceinline__ bool frac_gt(float i1, float d1, float i2, float d2) {
#pragma clang fp contract(off)
    float p1 = i1 * d2;
    float p2 = i2 * d1;
    float e1 = fmaf(i1, d2, -p1);
    float e2 = fmaf(i2, d1, -p2);
    return (p1 > p2) || ((p1 == p2) && (e1 > e2));
}

// Correctly-rounded f32 divide for our operand range (d in [16, ~5.7e4],
// n in [0, ~1.6e4]): the numerical core LLVM emits for `/` (rcp + NR + 2
// exact-residual FMA corrections) minus div_scale/div_fmas/div_fixup —
// bit-identical results (harness-validated rounds 1-6), no VCC dependency.
__device__ __forceinline__ float div_rn(float n, float d) {
    float y = __builtin_amdgcn_rcpf(d);
    float e = fmaf(-d, y, 1.0f);
    y = fmaf(e, y, y);
    float q = n * y;
    float r = fmaf(-d, q, n);
    q = fmaf(r, y, q);
    float r2 = fmaf(-d, q, n);
    return fmaf(r2, y, q);
}

// pack/unpack float2 <-> u64 for agent-scope 8B atomics
__device__ __forceinline__ unsigned long long pack2(float x, float y) {
    return (unsigned long long)__float_as_uint(x) |
           ((unsigned long long)__float_as_uint(y) << 32);
}
__device__ __forceinline__ void unpack2(unsigned long long u, float& x, float& y) {
    x = __uint_as_float((unsigned)(u & 0xffffffffu));
    y = __uint_as_float((unsigned)(u >> 32));
}

// --- kernel 1: per-gt max; last block per batch finalizes haux --------------
// grid (P1T, NB), block 512 = 8 waves, launch_bounds(512,8) => 4 blocks/CU
// (32 waves/CU, 100% occupancy ceiling). Wave w scans APWT anchors via
// uniform-address ds_read broadcast; 2-way split accumulators.
template<int P1T, int APWT>
__global__ __launch_bounds__(512, 8) void k_part_t(
        const float* __restrict__ anchors, const float* __restrict__ gts,
        float2* __restrict__ part /* [NB][P1T][NG] */,
        float2* __restrict__ haux /* [NB][NG] = {garea, highest} */) {
    constexpr int APB = 8 * APWT;                   // anchors per block
    __shared__ float4 sa[APB];
    __shared__ float  sar[APB];
    __shared__ float pi[8][NG], pd[8][NG];          // reused by reducer
    __shared__ int s_old;

    const int b = blockIdx.y;
    const int j = blockIdx.x;
    const int lane = threadIdx.x & 63;
    const int wid = __builtin_amdgcn_readfirstlane(threadIdx.x >> 6);

    const float4* __restrict__ anc =
        reinterpret_cast<const float4*>(anchors) + (size_t)b * NA;
    for (int t = threadIdx.x; t < APB; t += 512) {
        float4 v = anc[j * APB + t];                // coalesced burst
        sa[t]  = v;
        sar[t] = box_area(v.x, v.y, v.z, v.w);
    }

    float4 g = reinterpret_cast<const float4*>(gts)[b * NG + lane];
    float garea = box_area(g.x, g.y, g.z, g.w);
    __syncthreads();

    const int base = wid * APWT;
    float bi0 = 0.0f, bd0 = 1.0f;                   // even-anchor chain
    float bi1 = 0.0f, bd1 = 1.0f;                   // odd-anchor chain
#pragma unroll 4
    for (int i = 0; i < APWT; i += 2) {
        float4 a0 = sa[base + i];                   // uniform -> broadcast
        float  aa0 = sar[base + i];
        float4 a1 = sa[base + i + 1];
        float  aa1 = sar[base + i + 1];
        float i0, d0, i1, d1;
        inter_denom(g.x, g.y, g.z, g.w, garea, a0.x, a0.y, a0.z, a0.w, aa0, i0, d0);
        inter_denom(g.x, g.y, g.z, g.w, garea, a1.x, a1.y, a1.z, a1.w, aa1, i1, d1);
        if (frac_gt(i0, d0, bi0, bd0)) { bi0 = i0; bd0 = d0; }
        if (frac_gt(i1, d1, bi1, bd1)) { bi1 = i1; bd1 = d1; }
    }
    if (frac_gt(bi1, bd1, bi0, bd0)) { bi0 = bi1; bd0 = bd1; }

    pi[wid][lane] = bi0;
    pd[wid][lane] = bd0;
    __syncthreads();
    if (threadIdx.x < NG) {
        float ci = pi[0][threadIdx.x], cd = pd[0][threadIdx.x];
#pragma unroll
        for (int wv = 1; wv < 8; ++wv) {
            float ni = pi[wv][threadIdx.x], nd = pd[wv][threadIdx.x];
            if (frac_gt(ni, nd, ci, cd)) { ci = ni; cd = nd; }
        }
        // agent-scope publish: cross-XCD-coherent for the reducer block
        __hip_atomic_store(
            reinterpret_cast<unsigned long long*>(
                &part[((size_t)b * P1T + j) * NG + threadIdx.x]),
            pack2(ci, cd), __ATOMIC_RELAXED, __HIP_MEMORY_SCOPE_AGENT);
    }
    __syncthreads();                // drains the stores (waitcnt before barrier)
    if (threadIdx.x == 0) {
        __threadfence();            // device-scope release before the count
        s_old = atomicAdd(&g_ctr[b], 1);
    }
    __syncthreads();
    if ((s_old % P1T) != P1T - 1) return;

    // ---- last block for batch b: reduce P1T partials -> haux[b][g] ---------
    {
        const int gi = threadIdx.x & 63;
        const int c  = threadIdx.x >> 6;            // 8 chunks
        float ci = 0.0f, cd = 1.0f;
#pragma unroll 4
        for (int p = c; p < P1T; p += 8) {
            unsigned long long u = __hip_atomic_load(
                reinterpret_cast<const unsigned long long*>(
                    &part[((size_t)b * P1T + p) * NG + gi]),
                __ATOMIC_RELAXED, __HIP_MEMORY_SCOPE_AGENT);
            float ni, nd;
            unpack2(u, ni, nd);
            if (frac_gt(ni, nd, ci, cd)) { ci = ni; cd = nd; }
        }
        pi[c][gi] = ci;
        pd[c][gi] = cd;
    }
    __syncthreads();
    if (threadIdx.x < NG) {
        float ci = pi[0][threadIdx.x], cd = pd[0][threadIdx.x];
#pragma unroll
        for (int wv = 1; wv < 8; ++wv) {
            float ni = pi[wv][threadIdx.x], nd = pd[wv][threadIdx.x];
            if (frac_gt(ni, nd, ci, cd)) { ci = ni; cd = nd; }
        }
        float4 gv = reinterpret_cast<const float4*>(gts)[b * NG + threadIdx.x];
        // plain store: inter-dispatch coherence covers k_assign2's reads
        haux[b * NG + threadIdx.x] =
            make_float2(box_area(gv.x, gv.y, gv.z, gv.w), div_rn(ci, cd));
    }
}

// --- kernel 2: per-anchor match + labels (scalar-pipe gt reads) -------------
// grid (625, NB), block 256, ONE anchor per thread. Inner loop reads gt box
// (s_load_dwordx4) and {garea, highest} (s_load_dwordx2) with wave-uniform
// addresses — scalar pipe prefetches far ahead, zero LDS waits in the loop.
// LDS staging only for the cl-indexed epilogue; barrier AFTER the main loop.
__global__ __launch_bounds__(256, 8) void k_assign2(
        const float* __restrict__ anchors, const float* __restrict__ gts,
        const float* __restrict__ scores, const int* __restrict__ confs,
        const float2* __restrict__ haux,
        float* __restrict__ labels_out, float4* __restrict__ boxes_out) {
    __shared__ float4 sg[NG];       // gt box (epilogue only)
    __shared__ float  ssc[NG];
    __shared__ int    scf[NG];

    const int b = blockIdx.y;
    if (threadIdx.x < NG) {
        const int gi = threadIdx.x;
        sg[gi]  = reinterpret_cast<const float4*>(gts)[b * NG + gi];
        ssc[gi] = scores[b * NG + gi];
        scf[gi] = confs[b * NG + gi];
    }
    // NO barrier here: main loop doesn't touch LDS.

    const int ai = blockIdx.x * 256 + threadIdx.x;  // 0..159999 exactly
    const float4* __restrict__ anc =
        reinterpret_cast<const float4*>(anchors) + (size_t)b * NA;
    float4 av = anc[ai];
    float aarea = box_area(av.x, av.y, av.z, av.w);

    const float4* __restrict__ gt4 =
        reinterpret_cast<const float4*>(gts) + b * NG;
    const float2* __restrict__ hx = haux + b * NG;

    float best = -1.0f;             // all-zero row -> argmax 0 (first max)
    int   matches = 0;
    bool  lowq = false;
#pragma unroll 8
    for (int g = 0; g < NG; ++g) {
        float4 gb = gt4[g];                         // uniform -> s_load_dwordx4
        float2 ah = hx[g];                          // uniform -> s_load_dwordx2
        float inter, denom;
        inter_denom(gb.x, gb.y, gb.z, gb.w, ah.x,
                    av.x, av.y, av.z, av.w, aarea, inter, denom);
        float v = div_rn(inter, denom);             // bit-exact IEEE quotient
        if (v > best) { best = v; matches = g; }    // strict > keeps FIRST max
        lowq |= (v == ah.y);                        // bit-exact equality
    }

    int m    = (best < 0.3f) ? -1 : ((best < 0.7f) ? -2 : matches);
    int midx = lowq ? matches : m;
    int cl   = (midx < 0) ? 0 : midx;

    __syncthreads();                // staging issued ~3000 cycles ago
    float4 mg = sg[cl];
    float  sc = ssc[cl];
    int    cf = scf[cl];

    bool pos = (midx >= 0);
    float lab = pos ? 1.0f : 0.0f;
    lab = fminf(lab, sc);
    if (midx == -1) lab = 0.0f;
    if (midx == -2) lab = -1.0f;
    if (sc < 1.0f && pos) lab = -1.0f;
    if (cf == 0 && pos) lab = -1.0f;

    labels_out[(size_t)b * NA + ai] = lab;
    boxes_out[(size_t)b * NA + ai] = mg;
}

// --- fallback (ws too small even for P1=250): memset + atomicMax ------------
__global__ __launch_bounds__(256) void k_gt_highest_fb(
        const float* __restrict__ anchors, const float* __restrict__ gts,
        float* __restrict__ highest /* [B*G], pre-zeroed */) {
    const int b = blockIdx.y;
    const int lane = threadIdx.x & 63;
    const int wid = __builtin_amdgcn_readfirstlane(threadIdx.x >> 6);

    const float4* __restrict__ anc =
        reinterpret_cast<const float4*>(anchors) + (size_t)b * NA;
    float4 g = reinterpret_cast<const float4*>(gts)[b * NG + lane];
    float garea = box_area(g.x, g.y, g.z, g.w);

    const int base = blockIdx.x * 160 + wid * 40;
    float bi = 0.0f, bd = 1.0f;
#pragma unroll 8
    for (int i = 0; i < 40; ++i) {
        float4 a = anc[base + i];
        float aarea = box_area(a.x, a.y, a.z, a.w);
        float inter, denom;
        inter_denom(g.x, g.y, g.z, g.w, garea, a.x, a.y, a.z, a.w, aarea,
                    inter, denom);
        if (frac_gt(inter, denom, bi, bd)) { bi = inter; bd = denom; }
    }

    __shared__ float pi[4][NG], pd[4][NG];
    pi[wid][lane] = bi;
    pd[wid][lane] = bd;
    __syncthreads();
    if (threadIdx.x < NG) {
        float ci = pi[0][threadIdx.x], cd = pd[0][threadIdx.x];
#pragma unroll
        for (int wv = 1; wv < 4; ++wv) {
            float ni = pi[wv][threadIdx.x], nd = pd[wv][threadIdx.x];
            if (frac_gt(ni, nd, ci, cd)) { ci = ni; cd = nd; }
        }
        atomicMax(reinterpret_cast<int*>(&highest[b * NG + threadIdx.x]),
                  __float_as_int(div_rn(ci, cd)));
    }
}

__global__ __launch_bounds__(256) void k_assign_fb(
        const float* __restrict__ anchors, const float* __restrict__ gts,
        const float* __restrict__ scores, const int* __restrict__ confs,
        const float* __restrict__ highest,
        float* __restrict__ labels_out, float4* __restrict__ boxes_out) {
    __shared__ float4 sg[NG];
    __shared__ float2 sah[NG];
    __shared__ float  ssc[NG];
    __shared__ int    scf[NG];

    const int b = blockIdx.y;
    if (threadIdx.x < NG) {
        const int gi = threadIdx.x;
        float4 gv = reinterpret_cast<const float4*>(gts)[b * NG + gi];
        sg[gi]  = gv;
        sah[gi] = make_float2(box_area(gv.x, gv.y, gv.z, gv.w),
                              highest[b * NG + gi]);
        ssc[gi] = scores[b * NG + gi];
        scf[gi] = confs[b * NG + gi];
    }
    __syncthreads();

    const int ai = blockIdx.x * 256 + threadIdx.x;
    const float4* __restrict__ anc =
        reinterpret_cast<const float4*>(anchors) + (size_t)b * NA;
    float4 av = anc[ai];
    float aarea = box_area(av.x, av.y, av.z, av.w);

    float best = -1.0f;
    int   matches = 0;
    bool  lowq = false;
#pragma unroll 4
    for (int g = 0; g < NG; ++g) {
        float4 gb = sg[g];
        float2 ah = sah[g];
        float inter, denom;
        inter_denom(gb.x, gb.y, gb.z, gb.w, ah.x,
                    av.x, av.y, av.z, av.w, aarea, inter, denom);
        float v = div_rn(inter, denom);
        if (v > best) { best = v; matches = g; }
        lowq |= (v == ah.y);
    }

    int m    = (best < 0.3f) ? -1 : ((best < 0.7f) ? -2 : matches);
    int midx = lowq ? matches : m;
    int cl   = (midx < 0) ? 0 : midx;

    float4 mg = sg[cl];
    float  sc = ssc[cl];
    int    cf = scf[cl];

    bool pos = (midx >= 0);
    float lab = pos ? 1.0f : 0.0f;
    lab = fminf(lab, sc);
    if (midx == -1) lab = 0.0f;
    if (midx == -2) lab = -1.0f;
    if (sc < 1.0f && pos) lab = -1.0f;
    if (cf == 0 && pos) lab = -1.0f;

    labels_out[(size_t)b * NA + ai] = lab;
    boxes_out[(size_t)b * NA + ai] = mg;
}

extern "C" void kernel_launch(void* const* d_in, const int* in_sizes, int n_in,
                              void* d_out, int out_size, void* d_ws, size_t ws_size,
                              hipStream_t stream) {
    const float* anchors = (const float*)d_in[0];   // [B,A,4]
    const float* gts     = (const float*)d_in[1];   // [B,G,4]
    const float* scores  = (const float*)d_in[2];   // [B,G]
    const int*   confs   = (const int*)d_in[3];     // [B,G]

    float* labels_out = (float*)d_out;                              // [B,A]
    float4* boxes_out = (float4*)((float*)d_out + (size_t)NB * NA); // [B,A,4]

    const size_t haux_bytes = (size_t)NB * NG * sizeof(float2);     // 2 KB
    const size_t need500 = (size_t)NB * 500 * NG * sizeof(float2) + haux_bytes;
    const size_t need250 = (size_t)NB * 250 * NG * sizeof(float2) + haux_bytes;

    if (ws_size >= need500) {
        float2* part = (float2*)d_ws;
        float2* haux = (float2*)((char*)d_ws +
                                 (size_t)NB * 500 * NG * sizeof(float2));
        dim3 g1(500, NB), g2(625, NB);
        k_part_t<500, 40><<<g1, dim3(512), 0, stream>>>(anchors, gts, part, haux);
        k_assign2<<<g2, dim3(256), 0, stream>>>(anchors, gts, scores, confs,
                                                haux, labels_out, boxes_out);
    } else if (ws_size >= need250) {
        float2* part = (float2*)d_ws;
        float2* haux = (float2*)((char*)d_ws +
                                 (size_t)NB * 250 * NG * sizeof(float2));
        dim3 g1(250, NB), g2(625, NB);
        k_part_t<250, 80><<<g1, dim3(512), 0, stream>>>(anchors, gts, part, haux);
        k_assign2<<<g2, dim3(256), 0, stream>>>(anchors, gts, scores, confs,
                                                haux, labels_out, boxes_out);
    } else {
        float* highest = (float*)d_ws;
        hipMemsetAsync(d_ws, 0, (size_t)NB * NG * sizeof(float), stream);
        dim3 g1(1000, NB), g2(625, NB), blk(256);
        k_gt_highest_fb<<<g1, blk, 0, stream>>>(anchors, gts, highest);
        k_assign_fb<<<g2, blk, 0, stream>>>(anchors, gts, scores, confs,
                                            highest, labels_out, boxes_out);
    }
}

// Round 8
// 134.631 us; speedup vs baseline: 1.1880x; 1.1880x over previous
//
#include <hip/hip_runtime.h>

// Problem: B=4, A=160000 anchors, G=64 gt boxes.
// outputs (concat flat): labels [B,A] f32, matched_gt_boxes [B,A,4] f32
constexpr int NB = 4;
constexpr int NA = 160000;
constexpr int NG = 64;

// Two-dispatch scheme (round-6 proven shape):
//  k_part   : 1024-thr blocks, anchors+areas LDS-staged, 16 waves x 40
//             anchors; per-block partial per gt; LAST block per batch
//             (module epoch counter mod P1, replay-safe) reduces 250
//             partials -> haux[b][g] = {garea, highest, 0, 0}.
//  k_assign2: 1 anchor/thread, 2500 blocks; gt data via wave-uniform s_load
//             (two aligned dwordx4 per gt), unroll 16 for deep scalar
//             prefetch; LDS only for the cl-indexed epilogue (barrier after
//             the main loop).
constexpr int P1   = 250;         // k_part blocks per batch
constexpr int APB1 = NA / P1;     // 640 anchors per k_part block
constexpr int APW  = 40;          // anchors per wave (16 waves * 40 = 640)

// Module-scope counter: zero-initialized at module load, counted MODULO P1
// -> "last block per batch" works for every graph replay without a memset.
__device__ int g_ctr[NB];

// --- exact-rounding helpers -------------------------------------------------
// contract(off): stop fma fusion that would change rounding vs numpy.
__device__ __forceinline__ float box_area(float x0, float y0, float x1, float y1) {
#pragma clang fp contract(off)
    return (x1 - x0) * (y1 - y0);
}

// inter/denom with the exact op order of the numpy reference; shared by both
// kernels so phase-1's deferred quotient is bit-identical to phase-2's.
__device__ __forceinline__ void inter_denom(float gx0, float gy0, float gx1, float gy1, float garea,
                                            float ax0, float ay0, float ax1, float ay1, float aarea,
                                            float& inter, float& denom) {
#pragma clang fp contract(off)
    float ltx = fmaxf(gx0, ax0);
    float lty = fmaxf(gy0, ay0);
    float rbx = fminf(gx1, ax1);
    float rby = fminf(gy1, ay1);
    float w = fmaxf(rbx - ltx, 0.0f);
    float h = fmaxf(rby - lty, 0.0f);
    inter = w * h;
    float s = garea + aarea;        // numpy: area_gt + area_anchor
    denom = s - inter;
}

// exact comparison  i1/d1 > i2/d2  (all >= 0, d > 0), pure f32:
// FMA two-product gives the EXACT products p+e; ordering decided on the
// rounded products, ties broken on the exact tails (real-number ordering).
// Harness-validated bit-exact (absmax = 0.0, rounds 1-7).
__device__ __forceinline__ bool frac_gt(float i1, float d1, float i2, float d2) {
#pragma clang fp contract(off)
    float p1 = i1 * d2;
    float p2 = i2 * d1;
    float e1 = fmaf(i1, d2, -p1);
    float e2 = fmaf(i2, d1, -p2);
    return (p1 > p2) || ((p1 == p2) && (e1 > e2));
}

// Correctly-rounded f32 divide for our operand range (d in [16, ~5.7e4],
// n in [0, ~1.6e4]): the numerical core LLVM emits for `/` (rcp + NR + 2
// exact-residual FMA corrections) minus div_scale/div_fmas/div_fixup —
// bit-identical results (harness-validated rounds 1-7), no VCC dependency.
__device__ __forceinline__ float div_rn(float n, float d) {
    float y = __builtin_amdgcn_rcpf(d);
    float e = fmaf(-d, y, 1.0f);
    y = fmaf(e, y, y);
    float q = n * y;
    float r = fmaf(-d, q, n);
    q = fmaf(r, y, q);
    float r2 = fmaf(-d, q, n);
    return fmaf(r2, y, q);
}

// pack/unpack float2 <-> u64 for agent-scope 8B atomics
__device__ __forceinline__ unsigned long long pack2(float x, float y) {
    return (unsigned long long)__float_as_uint(x) |
           ((unsigned long long)__float_as_uint(y) << 32);
}
__device__ __forceinline__ void unpack2(unsigned long long u, float& x, float& y) {
    x = __uint_as_float((unsigned)(u & 0xffffffffu));
    y = __uint_as_float((unsigned)(u >> 32));
}

// --- kernel 1: per-gt max; last block per batch finalizes haux --------------
// grid (P1, NB), block 1024 = 16 waves (round-6 proven config, 44 us).
__global__ __launch_bounds__(1024, 8) void k_part(
        const float* __restrict__ anchors, const float* __restrict__ gts,
        float2* __restrict__ part /* [NB][P1][NG] */,
        float4* __restrict__ haux /* [NB][NG] = {garea, highest, 0, 0} */) {
    __shared__ float4 sa[APB1];                     // 640 anchors, 10 KB
    __shared__ float  sar[APB1];                    // areas, 2.5 KB
    __shared__ float pi[16][NG], pd[16][NG];        // 8 KB (reused by reducer)
    __shared__ int s_old;

    const int b = blockIdx.y;
    const int j = blockIdx.x;
    const int lane = threadIdx.x & 63;
    const int wid = __builtin_amdgcn_readfirstlane(threadIdx.x >> 6);

    const float4* __restrict__ anc =
        reinterpret_cast<const float4*>(anchors) + (size_t)b * NA;
    if (threadIdx.x < APB1) {
        float4 v = anc[j * APB1 + threadIdx.x];     // coalesced burst
        sa[threadIdx.x]  = v;
        sar[threadIdx.x] = box_area(v.x, v.y, v.z, v.w);
    }

    float4 g = reinterpret_cast<const float4*>(gts)[b * NG + lane];
    float garea = box_area(g.x, g.y, g.z, g.w);
    __syncthreads();

    const int base = wid * APW;
    float bi0 = 0.0f, bd0 = 1.0f;                   // even-anchor chain
    float bi1 = 0.0f, bd1 = 1.0f;                   // odd-anchor chain
#pragma unroll 4
    for (int i = 0; i < APW; i += 2) {
        float4 a0 = sa[base + i];                   // uniform -> broadcast
        float  aa0 = sar[base + i];
        float4 a1 = sa[base + i + 1];
        float  aa1 = sar[base + i + 1];
        float i0, d0, i1, d1;
        inter_denom(g.x, g.y, g.z, g.w, garea, a0.x, a0.y, a0.z, a0.w, aa0, i0, d0);
        inter_denom(g.x, g.y, g.z, g.w, garea, a1.x, a1.y, a1.z, a1.w, aa1, i1, d1);
        if (frac_gt(i0, d0, bi0, bd0)) { bi0 = i0; bd0 = d0; }
        if (frac_gt(i1, d1, bi1, bd1)) { bi1 = i1; bd1 = d1; }
    }
    if (frac_gt(bi1, bd1, bi0, bd0)) { bi0 = bi1; bd0 = bd1; }

    pi[wid][lane] = bi0;
    pd[wid][lane] = bd0;
    __syncthreads();
    if (threadIdx.x < NG) {
        float ci = pi[0][threadIdx.x], cd = pd[0][threadIdx.x];
#pragma unroll
        for (int wv = 1; wv < 16; ++wv) {
            float ni = pi[wv][threadIdx.x], nd = pd[wv][threadIdx.x];
            if (frac_gt(ni, nd, ci, cd)) { ci = ni; cd = nd; }
        }
        // agent-scope publish: cross-XCD-coherent for the reducer block
        __hip_atomic_store(
            reinterpret_cast<unsigned long long*>(
                &part[((size_t)b * P1 + j) * NG + threadIdx.x]),
            pack2(ci, cd), __ATOMIC_RELAXED, __HIP_MEMORY_SCOPE_AGENT);
    }
    __syncthreads();                // drains the stores (waitcnt before barrier)
    if (threadIdx.x == 0) {
        __threadfence();            // device-scope release before the count
        s_old = atomicAdd(&g_ctr[b], 1);
    }
    __syncthreads();
    if ((s_old % P1) != P1 - 1) return;

    // ---- last block for batch b: reduce 250 partials -> haux[b][g] ---------
    {
        const int gi = threadIdx.x & 63;
        const int c  = threadIdx.x >> 6;            // 16 chunks
        float ci = 0.0f, cd = 1.0f;
#pragma unroll 4
        for (int p = c; p < P1; p += 16) {
            unsigned long long u = __hip_atomic_load(
                reinterpret_cast<const unsigned long long*>(
                    &part[((size_t)b * P1 + p) * NG + gi]),
                __ATOMIC_RELAXED, __HIP_MEMORY_SCOPE_AGENT);
            float ni, nd;
            unpack2(u, ni, nd);
            if (frac_gt(ni, nd, ci, cd)) { ci = ni; cd = nd; }
        }
        pi[c][gi] = ci;
        pd[c][gi] = cd;
    }
    __syncthreads();
    if (threadIdx.x < NG) {
        float ci = pi[0][threadIdx.x], cd = pd[0][threadIdx.x];
#pragma unroll
        for (int wv = 1; wv < 16; ++wv) {
            float ni = pi[wv][threadIdx.x], nd = pd[wv][threadIdx.x];
            if (frac_gt(ni, nd, ci, cd)) { ci = ni; cd = nd; }
        }
        float4 gv = reinterpret_cast<const float4*>(gts)[b * NG + threadIdx.x];
        // plain store: inter-dispatch coherence covers k_assign2's reads
        haux[b * NG + threadIdx.x] =
            make_float4(box_area(gv.x, gv.y, gv.z, gv.w), div_rn(ci, cd),
                        0.0f, 0.0f);
    }
}

// --- kernel 2: per-anchor match + labels (scalar-pipe gt reads) -------------
// grid (625, NB), block 256, ONE anchor per thread. Inner loop reads gt box
// and {garea, highest} as TWO aligned s_load_dwordx4 with wave-uniform
// addresses; unroll 16 keeps ~32 scalar loads in flight (2 KB table is
// K$-resident after first touch). LDS only for the cl-indexed epilogue;
// barrier AFTER the main loop so staging latency hides under the compute.
__global__ __launch_bounds__(256, 8) void k_assign2(
        const float* __restrict__ anchors, const float* __restrict__ gts,
        const float* __restrict__ scores, const int* __restrict__ confs,
        const float4* __restrict__ haux,
        float* __restrict__ labels_out, float4* __restrict__ boxes_out) {
    __shared__ float4 sg[NG];       // gt box (epilogue only)
    __shared__ float  ssc[NG];
    __shared__ int    scf[NG];

    const int b = blockIdx.y;
    if (threadIdx.x < NG) {
        const int gi = threadIdx.x;
        sg[gi]  = reinterpret_cast<const float4*>(gts)[b * NG + gi];
        ssc[gi] = scores[b * NG + gi];
        scf[gi] = confs[b * NG + gi];
    }
    // NO barrier here: main loop doesn't touch LDS.

    const int ai = blockIdx.x * 256 + threadIdx.x;  // 0..159999 exactly
    const float4* __restrict__ anc =
        reinterpret_cast<const float4*>(anchors) + (size_t)b * NA;
    float4 av = anc[ai];
    float aarea = box_area(av.x, av.y, av.z, av.w);

    const float4* __restrict__ gt4 =
        reinterpret_cast<const float4*>(gts) + b * NG;
    const float4* __restrict__ hx = haux + b * NG;

    float best = -1.0f;             // all-zero row -> argmax 0 (first max)
    int   matches = 0;
    bool  lowq = false;
#pragma unroll 16
    for (int g = 0; g < NG; ++g) {
        float4 gb = gt4[g];                         // uniform -> s_load_dwordx4
        float4 ah = hx[g];                          // uniform -> s_load_dwordx4
        float inter, denom;
        inter_denom(gb.x, gb.y, gb.z, gb.w, ah.x,
                    av.x, av.y, av.z, av.w, aarea, inter, denom);
        float v = div_rn(inter, denom);             // bit-exact IEEE quotient
        if (v > best) { best = v; matches = g; }    // strict > keeps FIRST max
        lowq |= (v == ah.y);                        // bit-exact equality
    }

    int m    = (best < 0.3f) ? -1 : ((best < 0.7f) ? -2 : matches);
    int midx = lowq ? matches : m;
    int cl   = (midx < 0) ? 0 : midx;

    __syncthreads();                // staging issued ~3000 cycles ago
    float4 mg = sg[cl];
    float  sc = ssc[cl];
    int    cf = scf[cl];

    bool pos = (midx >= 0);
    float lab = pos ? 1.0f : 0.0f;
    lab = fminf(lab, sc);
    if (midx == -1) lab = 0.0f;
    if (midx == -2) lab = -1.0f;
    if (sc < 1.0f && pos) lab = -1.0f;
    if (cf == 0 && pos) lab = -1.0f;

    labels_out[(size_t)b * NA + ai] = lab;
    boxes_out[(size_t)b * NA + ai] = mg;
}

// --- fallback (ws too small): memset + atomicMax + LDS-loop assign ----------
__global__ __launch_bounds__(256) void k_gt_highest_fb(
        const float* __restrict__ anchors, const float* __restrict__ gts,
        float* __restrict__ highest /* [B*G], pre-zeroed */) {
    const int b = blockIdx.y;
    const int lane = threadIdx.x & 63;
    const int wid = __builtin_amdgcn_readfirstlane(threadIdx.x >> 6);

    const float4* __restrict__ anc =
        reinterpret_cast<const float4*>(anchors) + (size_t)b * NA;
    float4 g = reinterpret_cast<const float4*>(gts)[b * NG + lane];
    float garea = box_area(g.x, g.y, g.z, g.w);

    const int base = blockIdx.x * 160 + wid * 40;
    float bi = 0.0f, bd = 1.0f;
#pragma unroll 8
    for (int i = 0; i < 40; ++i) {
        float4 a = anc[base + i];
        float aarea = box_area(a.x, a.y, a.z, a.w);
        float inter, denom;
        inter_denom(g.x, g.y, g.z, g.w, garea, a.x, a.y, a.z, a.w, aarea,
                    inter, denom);
        if (frac_gt(inter, denom, bi, bd)) { bi = inter; bd = denom; }
    }

    __shared__ float pi[4][NG], pd[4][NG];
    pi[wid][lane] = bi;
    pd[wid][lane] = bd;
    __syncthreads();
    if (threadIdx.x < NG) {
        float ci = pi[0][threadIdx.x], cd = pd[0][threadIdx.x];
#pragma unroll
        for (int wv = 1; wv < 4; ++wv) {
            float ni = pi[wv][threadIdx.x], nd = pd[wv][threadIdx.x];
            if (frac_gt(ni, nd, ci, cd)) { ci = ni; cd = nd; }
        }
        atomicMax(reinterpret_cast<int*>(&highest[b * NG + threadIdx.x]),
                  __float_as_int(div_rn(ci, cd)));
    }
}

__global__ __launch_bounds__(256) void k_assign_fb(
        const float* __restrict__ anchors, const float* __restrict__ gts,
        const float* __restrict__ scores, const int* __restrict__ confs,
        const float* __restrict__ highest,
        float* __restrict__ labels_out, float4* __restrict__ boxes_out) {
    __shared__ float4 sg[NG];
    __shared__ float2 sah[NG];
    __shared__ float  ssc[NG];
    __shared__ int    scf[NG];

    const int b = blockIdx.y;
    if (threadIdx.x < NG) {
        const int gi = threadIdx.x;
        float4 gv = reinterpret_cast<const float4*>(gts)[b * NG + gi];
        sg[gi]  = gv;
        sah[gi] = make_float2(box_area(gv.x, gv.y, gv.z, gv.w),
                              highest[b * NG + gi]);
        ssc[gi] = scores[b * NG + gi];
        scf[gi] = confs[b * NG + gi];
    }
    __syncthreads();

    const int ai = blockIdx.x * 256 + threadIdx.x;
    const float4* __restrict__ anc =
        reinterpret_cast<const float4*>(anchors) + (size_t)b * NA;
    float4 av = anc[ai];
    float aarea = box_area(av.x, av.y, av.z, av.w);

    float best = -1.0f;
    int   matches = 0;
    bool  lowq = false;
#pragma unroll 4
    for (int g = 0; g < NG; ++g) {
        float4 gb = sg[g];
        float2 ah = sah[g];
        float inter, denom;
        inter_denom(gb.x, gb.y, gb.z, gb.w, ah.x,
                    av.x, av.y, av.z, av.w, aarea, inter, denom);
        float v = div_rn(inter, denom);
        if (v > best) { best = v; matches = g; }
        lowq |= (v == ah.y);
    }

    int m    = (best < 0.3f) ? -1 : ((best < 0.7f) ? -2 : matches);
    int midx = lowq ? matches : m;
    int cl   = (midx < 0) ? 0 : midx;

    float4 mg = sg[cl];
    float  sc = ssc[cl];
    int    cf = scf[cl];

    bool pos = (midx >= 0);
    float lab = pos ? 1.0f : 0.0f;
    lab = fminf(lab, sc);
    if (midx == -1) lab = 0.0f;
    if (midx == -2) lab = -1.0f;
    if (sc < 1.0f && pos) lab = -1.0f;
    if (cf == 0 && pos) lab = -1.0f;

    labels_out[(size_t)b * NA + ai] = lab;
    boxes_out[(size_t)b * NA + ai] = mg;
}

extern "C" void kernel_launch(void* const* d_in, const int* in_sizes, int n_in,
                              void* d_out, int out_size, void* d_ws, size_t ws_size,
                              hipStream_t stream) {
    const float* anchors = (const float*)d_in[0];   // [B,A,4]
    const float* gts     = (const float*)d_in[1];   // [B,G,4]
    const float* scores  = (const float*)d_in[2];   // [B,G]
    const int*   confs   = (const int*)d_in[3];     // [B,G]

    float* labels_out = (float*)d_out;                              // [B,A]
    float4* boxes_out = (float4*)((float*)d_out + (size_t)NB * NA); // [B,A,4]

    const size_t part_bytes = (size_t)NB * P1 * NG * sizeof(float2); // 512000
    const size_t need = part_bytes + (size_t)NB * NG * sizeof(float4);
    if (ws_size >= need) {
        float2* part = (float2*)d_ws;
        float4* haux = (float4*)((char*)d_ws + part_bytes);
        dim3 g1(P1, NB), g2(625, NB);
        k_part<<<g1, dim3(1024), 0, stream>>>(anchors, gts, part, haux);
        k_assign2<<<g2, dim3(256), 0, stream>>>(anchors, gts, scores, confs,
                                                haux, labels_out, boxes_out);
    } else {
        float* highest = (float*)d_ws;
        hipMemsetAsync(d_ws, 0, (size_t)NB * NG * sizeof(float), stream);
        dim3 g1(1000, NB), g2(625, NB), blk(256);
        k_gt_highest_fb<<<g1, blk, 0, stream>>>(anchors, gts, highest);
        k_assign_fb<<<g2, blk, 0, stream>>>(anchors, gts, scores, confs,
                                            highest, labels_out, boxes_out);
    }
}

// Round 9
// 128.786 us; speedup vs baseline: 1.2420x; 1.0454x over previous
//
#include <hip/hip_runtime.h>

// Problem: B=4, A=160000 anchors, G=64 gt boxes.
// outputs (concat flat): labels [B,A] f32, matched_gt_boxes [B,A,4] f32
constexpr int NB = 4;
constexpr int NA = 160000;
constexpr int NG = 64;

// Two-dispatch scheme:
//  k_part   : 1024-thr blocks, anchors+areas LDS-staged, 16 waves x 40
//             anchors. Per-gt max is a VALUE-max of rounded quotients
//             (bit-identical to the reference's mq.max(axis=1): rounding is
//             monotone, so max(round(x)) == round(max(x))) -> plain fmaxf
//             chains, NO exact-compare machinery, 1-op carried dependency.
//             4 anchors hand-batched per iteration (forces the allocator to
//             keep 4 loads + 4 div chains live; r6-r8 showed VGPR=12 when
//             left to the unroll pragma). LAST block per batch (module
//             epoch counter mod P1) reduces 250 float partials -> haux.
//  k_assign2: 1 anchor/thread, 2500 blocks; gt data via wave-uniform s_load
//             (two aligned dwordx4 per gt), unroll 16; LDS only for the
//             cl-indexed epilogue (barrier after the main loop). (r8 shape.)
constexpr int P1   = 250;         // k_part blocks per batch
constexpr int APB1 = NA / P1;     // 640 anchors per k_part block
constexpr int APW  = 40;          // anchors per wave (16 waves * 40 = 640)

// Module-scope counter: zero-initialized at module load, counted MODULO P1
// -> "last block per batch" works for every graph replay without a memset.
__device__ int g_ctr[NB];

// --- exact-rounding helpers -------------------------------------------------
// contract(off): stop fma fusion that would change rounding vs numpy.
__device__ __forceinline__ float box_area(float x0, float y0, float x1, float y1) {
#pragma clang fp contract(off)
    return (x1 - x0) * (y1 - y0);
}

// inter/denom with the exact op order of the numpy reference; shared by both
// kernels so phase-1's quotient is bit-identical to phase-2's.
__device__ __forceinline__ void inter_denom(float gx0, float gy0, float gx1, float gy1, float garea,
                                            float ax0, float ay0, float ax1, float ay1, float aarea,
                                            float& inter, float& denom) {
#pragma clang fp contract(off)
    float ltx = fmaxf(gx0, ax0);
    float lty = fmaxf(gy0, ay0);
    float rbx = fminf(gx1, ax1);
    float rby = fminf(gy1, ay1);
    float w = fmaxf(rbx - ltx, 0.0f);
    float h = fmaxf(rby - lty, 0.0f);
    inter = w * h;
    float s = garea + aarea;        // numpy: area_gt + area_anchor
    denom = s - inter;
}

// exact comparison i1/d1 > i2/d2 — kept ONLY for the fallback path.
__device__ __forceinline__ bool frac_gt(float i1, float d1, float i2, float d2) {
#pragma clang fp contract(off)
    float p1 = i1 * d2;
    float p2 = i2 * d1;
    float e1 = fmaf(i1, d2, -p1);
    float e2 = fmaf(i2, d1, -p2);
    return (p1 > p2) || ((p1 == p2) && (e1 > e2));
}

// Correctly-rounded f32 divide for our operand range (d in [16, ~5.7e4],
// n in [0, ~1.6e4]): the numerical core LLVM emits for `/` (rcp + NR + 2
// exact-residual FMA corrections) minus div_scale/div_fmas/div_fixup —
// bit-identical results (harness-validated rounds 1-8), no VCC dependency,
// so independent chains pipeline freely.
__device__ __forceinline__ float div_rn(float n, float d) {
    float y = __builtin_amdgcn_rcpf(d);
    float e = fmaf(-d, y, 1.0f);
    y = fmaf(e, y, y);
    float q = n * y;
    float r = fmaf(-d, q, n);
    q = fmaf(r, y, q);
    float r2 = fmaf(-d, q, n);
    return fmaf(r2, y, q);
}

// full rounded IoU of (g, garea) vs (a, aarea)
__device__ __forceinline__ float iou_q(float4 g, float garea, float4 a, float aarea) {
    float inter, denom;
    inter_denom(g.x, g.y, g.z, g.w, garea, a.x, a.y, a.z, a.w, aarea,
                inter, denom);
    return div_rn(inter, denom);
}

// --- kernel 1: per-gt max IoU; last block per batch finalizes haux ----------
// grid (P1, NB), block 1024 = 16 waves, launch_bounds(1024,8): VGPR cap 64.
__global__ __launch_bounds__(1024, 8) void k_part(
        const float* __restrict__ anchors, const float* __restrict__ gts,
        float* __restrict__ part /* [NB][P1][NG] float vmax */,
        float4* __restrict__ haux /* [NB][NG] = {garea, highest, 0, 0} */) {
    __shared__ float4 sa[APB1];                     // 640 anchors, 10 KB
    __shared__ float  sar[APB1];                    // areas, 2.5 KB
    __shared__ float  pi[16][NG];                   // 4 KB (reused by reducer)
    __shared__ int s_old;

    const int b = blockIdx.y;
    const int j = blockIdx.x;
    const int lane = threadIdx.x & 63;
    const int wid = __builtin_amdgcn_readfirstlane(threadIdx.x >> 6);

    const float4* __restrict__ anc =
        reinterpret_cast<const float4*>(anchors) + (size_t)b * NA;
    if (threadIdx.x < APB1) {
        float4 v = anc[j * APB1 + threadIdx.x];     // coalesced burst
        sa[threadIdx.x]  = v;
        sar[threadIdx.x] = box_area(v.x, v.y, v.z, v.w);
    }

    float4 g = reinterpret_cast<const float4*>(gts)[b * NG + lane];
    float garea = box_area(g.x, g.y, g.z, g.w);
    __syncthreads();

    const int base = wid * APW;
    // 4 independent fmax chains; 4 anchors' loads + div chains live at once.
    float vm0 = 0.0f, vm1 = 0.0f, vm2 = 0.0f, vm3 = 0.0f;
    for (int i = 0; i < APW; i += 4) {
        float4 a0 = sa[base + i];     float aa0 = sar[base + i];
        float4 a1 = sa[base + i + 1]; float aa1 = sar[base + i + 1];
        float4 a2 = sa[base + i + 2]; float aa2 = sar[base + i + 2];
        float4 a3 = sa[base + i + 3]; float aa3 = sar[base + i + 3];
        float v0 = iou_q(g, garea, a0, aa0);
        float v1 = iou_q(g, garea, a1, aa1);
        float v2 = iou_q(g, garea, a2, aa2);
        float v3 = iou_q(g, garea, a3, aa3);
        vm0 = fmaxf(vm0, v0);
        vm1 = fmaxf(vm1, v1);
        vm2 = fmaxf(vm2, v2);
        vm3 = fmaxf(vm3, v3);
    }
    float vmax = fmaxf(fmaxf(vm0, vm1), fmaxf(vm2, vm3));

    pi[wid][lane] = vmax;
    __syncthreads();
    if (threadIdx.x < NG) {
        float cv = pi[0][threadIdx.x];
#pragma unroll
        for (int wv = 1; wv < 16; ++wv) cv = fmaxf(cv, pi[wv][threadIdx.x]);
        // agent-scope publish: cross-XCD-coherent for the reducer block
        __hip_atomic_store(
            reinterpret_cast<unsigned int*>(
                &part[((size_t)b * P1 + j) * NG + threadIdx.x]),
            __float_as_uint(cv), __ATOMIC_RELAXED, __HIP_MEMORY_SCOPE_AGENT);
    }
    __syncthreads();                // drains the stores (waitcnt before barrier)
    if (threadIdx.x == 0) {
        __threadfence();            // device-scope release before the count
        s_old = atomicAdd(&g_ctr[b], 1);
    }
    __syncthreads();
    if ((s_old % P1) != P1 - 1) return;

    // ---- last block for batch b: reduce 250 partials -> haux[b][g] ---------
    {
        const int gi = threadIdx.x & 63;
        const int c  = threadIdx.x >> 6;            // 16 chunks
        float cv = 0.0f;
#pragma unroll 4
        for (int p = c; p < P1; p += 16) {
            unsigned int u = __hip_atomic_load(
                reinterpret_cast<const unsigned int*>(
                    &part[((size_t)b * P1 + p) * NG + gi]),
                __ATOMIC_RELAXED, __HIP_MEMORY_SCOPE_AGENT);
            cv = fmaxf(cv, __uint_as_float(u));
        }
        pi[c][gi] = cv;
    }
    __syncthreads();
    if (threadIdx.x < NG) {
        float cv = pi[0][threadIdx.x];
#pragma unroll
        for (int wv = 1; wv < 16; ++wv) cv = fmaxf(cv, pi[wv][threadIdx.x]);
        float4 gv = reinterpret_cast<const float4*>(gts)[b * NG + threadIdx.x];
        // plain store: inter-dispatch coherence covers k_assign2's reads
        haux[b * NG + threadIdx.x] =
            make_float4(box_area(gv.x, gv.y, gv.z, gv.w), cv, 0.0f, 0.0f);
    }
}

// --- kernel 2: per-anchor match + labels (r8 shape, unchanged) --------------
__global__ __launch_bounds__(256, 8) void k_assign2(
        const float* __restrict__ anchors, const float* __restrict__ gts,
        const float* __restrict__ scores, const int* __restrict__ confs,
        const float4* __restrict__ haux,
        float* __restrict__ labels_out, float4* __restrict__ boxes_out) {
    __shared__ float4 sg[NG];       // gt box (epilogue only)
    __shared__ float  ssc[NG];
    __shared__ int    scf[NG];

    const int b = blockIdx.y;
    if (threadIdx.x < NG) {
        const int gi = threadIdx.x;
        sg[gi]  = reinterpret_cast<const float4*>(gts)[b * NG + gi];
        ssc[gi] = scores[b * NG + gi];
        scf[gi] = confs[b * NG + gi];
    }
    // NO barrier here: main loop doesn't touch LDS.

    const int ai = blockIdx.x * 256 + threadIdx.x;  // 0..159999 exactly
    const float4* __restrict__ anc =
        reinterpret_cast<const float4*>(anchors) + (size_t)b * NA;
    float4 av = anc[ai];
    float aarea = box_area(av.x, av.y, av.z, av.w);

    const float4* __restrict__ gt4 =
        reinterpret_cast<const float4*>(gts) + b * NG;
    const float4* __restrict__ hx = haux + b * NG;

    float best = -1.0f;             // all-zero row -> argmax 0 (first max)
    int   matches = 0;
    bool  lowq = false;
#pragma unroll 16
    for (int g = 0; g < NG; ++g) {
        float4 gb = gt4[g];                         // uniform -> s_load_dwordx4
        float4 ah = hx[g];                          // uniform -> s_load_dwordx4
        float inter, denom;
        inter_denom(gb.x, gb.y, gb.z, gb.w, ah.x,
                    av.x, av.y, av.z, av.w, aarea, inter, denom);
        float v = div_rn(inter, denom);             // bit-exact IEEE quotient
        if (v > best) { best = v; matches = g; }    // strict > keeps FIRST max
        lowq |= (v == ah.y);                        // bit-exact equality
    }

    int m    = (best < 0.3f) ? -1 : ((best < 0.7f) ? -2 : matches);
    int midx = lowq ? matches : m;
    int cl   = (midx < 0) ? 0 : midx;

    __syncthreads();                // staging issued ~3000 cycles ago
    float4 mg = sg[cl];
    float  sc = ssc[cl];
    int    cf = scf[cl];

    bool pos = (midx >= 0);
    float lab = pos ? 1.0f : 0.0f;
    lab = fminf(lab, sc);
    if (midx == -1) lab = 0.0f;
    if (midx == -2) lab = -1.0f;
    if (sc < 1.0f && pos) lab = -1.0f;
    if (cf == 0 && pos) lab = -1.0f;

    labels_out[(size_t)b * NA + ai] = lab;
    boxes_out[(size_t)b * NA + ai] = mg;
}

// --- fallback (ws too small): memset + atomicMax + LDS-loop assign ----------
__global__ __launch_bounds__(256) void k_gt_highest_fb(
        const float* __restrict__ anchors, const float* __restrict__ gts,
        float* __restrict__ highest /* [B*G], pre-zeroed */) {
    const int b = blockIdx.y;
    const int lane = threadIdx.x & 63;
    const int wid = __builtin_amdgcn_readfirstlane(threadIdx.x >> 6);

    const float4* __restrict__ anc =
        reinterpret_cast<const float4*>(anchors) + (size_t)b * NA;
    float4 g = reinterpret_cast<const float4*>(gts)[b * NG + lane];
    float garea = box_area(g.x, g.y, g.z, g.w);

    const int base = blockIdx.x * 160 + wid * 40;
    float bi = 0.0f, bd = 1.0f;
#pragma unroll 8
    for (int i = 0; i < 40; ++i) {
        float4 a = anc[base + i];
        float aarea = box_area(a.x, a.y, a.z, a.w);
        float inter, denom;
        inter_denom(g.x, g.y, g.z, g.w, garea, a.x, a.y, a.z, a.w, aarea,
                    inter, denom);
        if (frac_gt(inter, denom, bi, bd)) { bi = inter; bd = denom; }
    }

    __shared__ float pi[4][NG], pd[4][NG];
    pi[wid][lane] = bi;
    pd[wid][lane] = bd;
    __syncthreads();
    if (threadIdx.x < NG) {
        float ci = pi[0][threadIdx.x], cd = pd[0][threadIdx.x];
#pragma unroll
        for (int wv = 1; wv < 4; ++wv) {
            float ni = pi[wv][threadIdx.x], nd = pd[wv][threadIdx.x];
            if (frac_gt(ni, nd, ci, cd)) { ci = ni; cd = nd; }
        }
        atomicMax(reinterpret_cast<int*>(&highest[b * NG + threadIdx.x]),
                  __float_as_int(div_rn(ci, cd)));
    }
}

__global__ __launch_bounds__(256) void k_assign_fb(
        const float* __restrict__ anchors, const float* __restrict__ gts,
        const float* __restrict__ scores, const int* __restrict__ confs,
        const float* __restrict__ highest,
        float* __restrict__ labels_out, float4* __restrict__ boxes_out) {
    __shared__ float4 sg[NG];
    __shared__ float2 sah[NG];
    __shared__ float  ssc[NG];
    __shared__ int    scf[NG];

    const int b = blockIdx.y;
    if (threadIdx.x < NG) {
        const int gi = threadIdx.x;
        float4 gv = reinterpret_cast<const float4*>(gts)[b * NG + gi];
        sg[gi]  = gv;
        sah[gi] = make_float2(box_area(gv.x, gv.y, gv.z, gv.w),
                              highest[b * NG + gi]);
        ssc[gi] = scores[b * NG + gi];
        scf[gi] = confs[b * NG + gi];
    }
    __syncthreads();

    const int ai = blockIdx.x * 256 + threadIdx.x;
    const float4* __restrict__ anc =
        reinterpret_cast<const float4*>(anchors) + (size_t)b * NA;
    float4 av = anc[ai];
    float aarea = box_area(av.x, av.y, av.z, av.w);

    float best = -1.0f;
    int   matches = 0;
    bool  lowq = false;
#pragma unroll 4
    for (int g = 0; g < NG; ++g) {
        float4 gb = sg[g];
        float2 ah = sah[g];
        float inter, denom;
        inter_denom(gb.x, gb.y, gb.z, gb.w, ah.x,
                    av.x, av.y, av.z, av.w, aarea, inter, denom);
        float v = div_rn(inter, denom);
        if (v > best) { best = v; matches = g; }
        lowq |= (v == ah.y);
    }

    int m    = (best < 0.3f) ? -1 : ((best < 0.7f) ? -2 : matches);
    int midx = lowq ? matches : m;
    int cl   = (midx < 0) ? 0 : midx;

    float4 mg = sg[cl];
    float  sc = ssc[cl];
    int    cf = scf[cl];

    bool pos = (midx >= 0);
    float lab = pos ? 1.0f : 0.0f;
    lab = fminf(lab, sc);
    if (midx == -1) lab = 0.0f;
    if (midx == -2) lab = -1.0f;
    if (sc < 1.0f && pos) lab = -1.0f;
    if (cf == 0 && pos) lab = -1.0f;

    labels_out[(size_t)b * NA + ai] = lab;
    boxes_out[(size_t)b * NA + ai] = mg;
}

extern "C" void kernel_launch(void* const* d_in, const int* in_sizes, int n_in,
                              void* d_out, int out_size, void* d_ws, size_t ws_size,
                              hipStream_t stream) {
    const float* anchors = (const float*)d_in[0];   // [B,A,4]
    const float* gts     = (const float*)d_in[1];   // [B,G,4]
    const float* scores  = (const float*)d_in[2];   // [B,G]
    const int*   confs   = (const int*)d_in[3];     // [B,G]

    float* labels_out = (float*)d_out;                              // [B,A]
    float4* boxes_out = (float4*)((float*)d_out + (size_t)NB * NA); // [B,A,4]

    const size_t part_bytes = (size_t)NB * P1 * NG * sizeof(float);  // 256000
    const size_t need = part_bytes + (size_t)NB * NG * sizeof(float4);
    if (ws_size >= need) {
        float* part  = (float*)d_ws;
        float4* haux = (float4*)((char*)d_ws + part_bytes);
        dim3 g1(P1, NB), g2(625, NB);
        k_part<<<g1, dim3(1024), 0, stream>>>(anchors, gts, part, haux);
        k_assign2<<<g2, dim3(256), 0, stream>>>(anchors, gts, scores, confs,
                                                haux, labels_out, boxes_out);
    } else {
        float* highest = (float*)d_ws;
        hipMemsetAsync(d_ws, 0, (size_t)NB * NG * sizeof(float), stream);
        dim3 g1(1000, NB), g2(625, NB), blk(256);
        k_gt_highest_fb<<<g1, blk, 0, stream>>>(anchors, gts, highest);
        k_assign_fb<<<g2, blk, 0, stream>>>(anchors, gts, scores, confs,
                                            highest, labels_out, boxes_out);
    }
}